// Round 9
// baseline (324.391 us; speedup 1.0000x reference)
//
#include <hip/hip_runtime.h>
#include <hip/hip_bf16.h>
#include <stdint.h>

#define B_    4
#define L_    2048
#define H_    16
#define DH_   64
#define DM_   1024
#define M_    8192
#define WIN_  512

typedef short  short8 __attribute__((ext_vector_type(8)));
typedef __bf16 bf16x8 __attribute__((ext_vector_type(8)));
typedef float  f32x4  __attribute__((ext_vector_type(4)));
typedef unsigned short us4 __attribute__((ext_vector_type(4)));

__device__ __forceinline__ unsigned short f2bf(float f) {
  return __builtin_bit_cast(unsigned short, __float2bfloat16(f));
}
__device__ __forceinline__ f32x4 mfma16(short8 a, short8 b, f32x4 c) {
  return __builtin_amdgcn_mfma_f32_16x16x32_bf16(
      __builtin_bit_cast(bf16x8, a), __builtin_bit_cast(bf16x8, b), c, 0, 0, 0);
}
__device__ __forceinline__ void async16(const void* g, void* lds) {
  __builtin_amdgcn_global_load_lds(
      (const __attribute__((address_space(1))) void*)g,
      (__attribute__((address_space(3))) void*)lds, 16, 0, 0);
}
template<int N> __device__ __forceinline__ void vmwait() {
  if constexpr (N == 4)      asm volatile("s_waitcnt vmcnt(4)" ::: "memory");
  else                       asm volatile("s_waitcnt vmcnt(0)" ::: "memory");
}

// ---------------- kernel 0a: fp32 -> bf16 convert ----------------
__global__ __launch_bounds__(256) void k_cvt(const float* __restrict__ in,
                                             unsigned short* __restrict__ out, int n) {
  int idx = (blockIdx.x * 256 + threadIdx.x) * 4;
  if (idx >= n) return;
  float4 f = *(const float4*)(in + idx);
  us4 o;
  o[0] = f2bf(f.x); o[1] = f2bf(f.y); o[2] = f2bf(f.z); o[3] = f2bf(f.w);
  *(us4*)(out + idx) = o;
}

// ---------- kernel 0b: convert + transpose W (Kdim x N_) -> (N_ x Kdim) bf16 ----------
__global__ __launch_bounds__(256) void k_wt(const float* __restrict__ W,
                                            unsigned short* __restrict__ WT, int N_) {
  __shared__ unsigned short t[32][33];
  int n0 = blockIdx.x * 32, k0 = blockIdx.y * 32;
  int tid = threadIdx.x;
  int r = tid >> 3, c4 = (tid & 7) * 4;
  float4 f = *(const float4*)(W + (size_t)(k0 + r) * N_ + n0 + c4);
  t[r][c4 + 0] = f2bf(f.x); t[r][c4 + 1] = f2bf(f.y);
  t[r][c4 + 2] = f2bf(f.z); t[r][c4 + 3] = f2bf(f.w);
  __syncthreads();
  unsigned short* dst = WT + (size_t)(n0 + r) * 1024 + k0 + c4;
  dst[0] = t[c4 + 0][r]; dst[1] = t[c4 + 1][r];
  dst[2] = t[c4 + 2][r]; dst[3] = t[c4 + 3][r];
}

// ---------------- kernel 0d: rotary tables cos/sin [L_][16] ----------------
__global__ __launch_bounds__(256) void k_rope(float* __restrict__ C, float* __restrict__ S) {
  int idx = blockIdx.x * 256 + threadIdx.x;   // 0..32767
  int tpos = idx >> 4, fi = idx & 15;
  float freq = 1.0f / powf(10000.0f, (float)fi / 16.0f);
  float a = (float)tpos * freq;
  C[idx] = cosf(a);
  S[idx] = sinf(a);
}

// ======== 128x128 triple-buffered MFMA GEMM core (K=1024, BK=32) ========
// Linear grid, m fastest: default XCD round-robin keeps a 2MB A-stripe/XCD L2.
__device__ __forceinline__ void gemm128(const unsigned short* __restrict__ A,
                                        const unsigned short* __restrict__ Bt,
                                        int m0, int n0, unsigned short* lds,
                                        f32x4 (&acc)[4][4]) {
  constexpr int SLOT = 8192;                    // (128+128)*32 elements
  const int tid = threadIdx.x, lane = tid & 63;
  const int wave = tid >> 6, wn = wave & 1, wm = wave >> 1;
  const int llo = lane & 15, lhi = lane >> 4;
  const int swz = (llo >> 1) & 3;
  const int rbase = wm * 64, cbase = wn * 64;

  auto stage = [&](int t) {
    unsigned short* s = lds + (t % 3) * SLOT;
    const int kt = t * 32;
#pragma unroll
    for (int i = 0; i < 2; ++i) {               // A: 512 16B-chunks
      int q = i * 256 + tid;
      int row = q >> 2, cs = (q & 3) ^ ((row >> 1) & 3);
      async16(A + (size_t)(m0 + row) * DM_ + kt + cs * 8, s + q * 8);
    }
#pragma unroll
    for (int i = 0; i < 2; ++i) {               // B: 512 16B-chunks
      int q = i * 256 + tid;
      int row = q >> 2, cs = (q & 3) ^ ((row >> 1) & 3);
      async16(Bt + (size_t)(n0 + row) * DM_ + kt + cs * 8, s + 4096 + q * 8);
    }
  };

  stage(0); stage(1);
#pragma unroll 4
  for (int t = 0; t < 32; ++t) {
    if (t < 31) vmwait<4>(); else vmwait<0>();  // tile t landed; t+1 stays in flight
    __builtin_amdgcn_s_barrier();               // all waves done reading tile t-1
    if (t + 2 < 32) stage(t + 2);               // overwrites slot (t-1)%3 - safe
    const unsigned short* sa = lds + (t % 3) * SLOT;
    const unsigned short* sb = sa + 4096;
    short8 af[4], bf[4];
#pragma unroll
    for (int i = 0; i < 4; ++i)
      af[i] = *(const short8*)(sa + (rbase + i * 16 + llo) * 32 + ((lhi ^ swz) << 3));
#pragma unroll
    for (int j = 0; j < 4; ++j)
      bf[j] = *(const short8*)(sb + (cbase + j * 16 + llo) * 32 + ((lhi ^ swz) << 3));
    __builtin_amdgcn_s_setprio(1);
#pragma unroll
    for (int i = 0; i < 4; ++i)
#pragma unroll
      for (int j = 0; j < 4; ++j)
        acc[i][j] = mfma16(af[i], bf[j], acc[i][j]);
    __builtin_amdgcn_s_setprio(0);
  }
}

// ---------------- kernel 1: qkv GEMM + rotary epilogue (128x128 tile) ----------------
// V is written directly in transposed (B,H,64,L) layout -> no separate k_vt pass.
__global__ __launch_bounds__(256, 3) void k_gemm_qkv(const unsigned short* __restrict__ X,
                                                     const unsigned short* __restrict__ WT,
                                                     unsigned short* __restrict__ Q,
                                                     unsigned short* __restrict__ Kq,
                                                     unsigned short* __restrict__ VT,
                                                     const float* __restrict__ COS,
                                                     const float* __restrict__ SIN) {
  __shared__ unsigned short lds[3 * 8192];   // 48 KiB
  const int wgid = blockIdx.x;               // linear, m fastest (see gemm128 note)
  const int m0 = (wgid & 63) * 128, n0 = (wgid >> 6) * 128;
  f32x4 acc[4][4];
#pragma unroll
  for (int i = 0; i < 4; ++i)
#pragma unroll
    for (int j = 0; j < 4; ++j) acc[i][j] = f32x4{0.f, 0.f, 0.f, 0.f};

  gemm128(X, WT, m0, n0, lds, acc);

  const int tid = threadIdx.x, lane = tid & 63;
  const int wave = tid >> 6, wn = wave & 1, wm = wave >> 1;
  const int llo = lane & 15, lhi = lane >> 4;
  const int ncol = n0 + wn * 64;         // one 64-col head-section per wave
  const int sec = ncol >> 10;            // 0=q 1=k 2=v
  const int h = (ncol & 1023) >> 6;
  unsigned short* dst = (sec == 0) ? Q : Kq;
  const bool rot = (sec < 2);
  // Q prescale: 0.125 (softmax scale) * log2(e) -> scores land in log2 domain
  const float qs = (sec == 0) ? 0.18033688f : 1.0f;
#pragma unroll
  for (int i = 0; i < 4; ++i) {
#pragma unroll
    for (int r = 0; r < 4; ++r) {
      int m = m0 + wm * 64 + i * 16 + lhi * 4 + r;     // global token
      int b = m >> 11, l = m & 2047;
      float c0 = acc[i][0][r], c1 = acc[i][1][r];
      float c2 = acc[i][2][r], c3 = acc[i][3][r];
      if (rot) {
        float cs = COS[l * 16 + llo], sn = SIN[l * 16 + llo];
        float n0v = c0 * cs - c1 * sn;
        float n1v = c1 * cs + c0 * sn;
        c0 = n0v; c1 = n1v;
        c0 *= qs; c1 *= qs; c2 *= qs; c3 *= qs;
        size_t base = ((size_t)(b * H_ + h) * L_ + l) * DH_;
        dst[base +      llo] = f2bf(c0);
        dst[base + 16 + llo] = f2bf(c1);
        dst[base + 32 + llo] = f2bf(c2);
        dst[base + 48 + llo] = f2bf(c3);
      } else {
        // V -> transposed layout VT[(bh*64 + d)*L + l], d = j*16+llo
        size_t vb = ((size_t)(b * H_ + h) * DH_ + llo) * L_ + l;
        VT[vb            ] = f2bf(c0);
        VT[vb + 16 * L_  ] = f2bf(c1);
        VT[vb + 32 * L_  ] = f2bf(c2);
        VT[vb + 48 * L_  ] = f2bf(c3);
      }
    }
  }
}

// ---------------- kernel 4: out GEMM (128x128 tile, fp32 epilogue) ----------------
__global__ __launch_bounds__(256, 3) void k_gemm_out(const unsigned short* __restrict__ A,
                                                     const unsigned short* __restrict__ WT,
                                                     float* __restrict__ Cout) {
  __shared__ unsigned short lds[3 * 8192];   // 48 KiB
  const int wgid = blockIdx.x;               // linear, m fastest
  const int m0 = (wgid & 63) * 128, n0 = (wgid >> 6) * 128;
  f32x4 acc[4][4];
#pragma unroll
  for (int i = 0; i < 4; ++i)
#pragma unroll
    for (int j = 0; j < 4; ++j) acc[i][j] = f32x4{0.f, 0.f, 0.f, 0.f};

  gemm128(A, WT, m0, n0, lds, acc);

  const int tid = threadIdx.x, lane = tid & 63;
  const int wave = tid >> 6, wn = wave & 1, wm = wave >> 1;
  const int llo = lane & 15, lhi = lane >> 4;
#pragma unroll
  for (int i = 0; i < 4; ++i)
#pragma unroll
    for (int r = 0; r < 4; ++r) {
      int m = m0 + wm * 64 + i * 16 + lhi * 4 + r;
#pragma unroll
      for (int j = 0; j < 4; ++j)
        Cout[(size_t)m * DM_ + n0 + wn * 64 + j * 16 + llo] = acc[i][j][r];
    }
}

// ---------------- kernel 3: barrier-free direct-L2 flash attention ----------------
// Wave = 32 q-rows, independent. Swapped QK^T (scores lane-local, log2 domain).
// Defer-max: common path has zero cross-lane ops. 4 blocks/CU resident
// (grid 1024 = exactly 4/CU, one round; qs flip balances per-CU work).
__global__ __launch_bounds__(256, 4) void k_attn(const unsigned short* __restrict__ Q,
                                                 const unsigned short* __restrict__ Kg,
                                                 const unsigned short* __restrict__ VT,
                                                 unsigned short* __restrict__ CTX) {
  __shared__ unsigned short lp[4][2048];   // per-wave P: 32 rows x 64 keys, swizzled
  const int tid = threadIdx.x, wave = tid >> 6, lane = tid & 63;
  const int bh = blockIdx.x;
  const int qs = 15 - blockIdx.y;          // heavy (long-window) blocks dispatch first
  const int wq0 = qs * 128 + wave * 32;
  const int llo = lane & 15, lhi = lane >> 4;

  // Q as B-fragment (prescaled by 0.125*log2e in qkv epilogue)
  short8 qa[2][2];
#pragma unroll
  for (int f = 0; f < 2; ++f) {
    const short8* qp = (const short8*)(Q + ((size_t)bh * L_ + wq0 + f * 16 + llo) * DH_ + lhi * 8);
    qa[f][0] = __builtin_nontemporal_load(qp);
    qa[f][1] = __builtin_nontemporal_load(qp + 4);
  }

  f32x4 ctxa[2][4];
#pragma unroll
  for (int f = 0; f < 2; ++f)
#pragma unroll
    for (int j = 0; j < 4; ++j) ctxa[f][j] = f32x4{0.f, 0.f, 0.f, 0.f};
  float m_q[2] = {-1e30f, -1e30f};         // running max (log2 units), quad-uniform
  float l_q[2] = {0.f, 0.f};               // lane-PARTIAL denom (this lane's 16 keys)

  const int t0 = (wq0 > (WIN_ - 1) ? wq0 - (WIN_ - 1) : 0) >> 6;
  const int t1 = (wq0 + 31) >> 6;
  const unsigned short* Kb_ = Kg + (size_t)bh * L_ * DH_;
  const unsigned short* Vb_ = VT + (size_t)bh * DH_ * L_;
  char* lpw = (char*)lp[wave];
  const int psw = (llo & 7);               // P swizzle key (row-derived)

  short8 kb[8];                            // K A-frag: row=key(k0+j*16+llo), k=dim lhi*8+e
  auto loadK = [&](int t) {
    const int k0 = t * 64;
#pragma unroll
    for (int j = 0; j < 4; ++j) {
      const short8* p = (const short8*)(Kb_ + (size_t)(k0 + j * 16 + llo) * DH_ + lhi * 8);
      kb[2 * j] = p[0];
      kb[2 * j + 1] = p[4];
    }
  };
  loadK(t0);

  for (int t = t0; t <= t1; ++t) {
    const int k0 = t * 64;
    const bool interior = (k0 + 63 <= wq0) && (k0 >= wq0 - (WIN_ - 32));
    // V B-frag loads (needed after softmax, latency hidden)
    short8 vb[8];
#pragma unroll
    for (int j = 0; j < 4; ++j) {
      const short8* p = (const short8*)(Vb_ + (size_t)(j * 16 + llo) * L_ + k0 + lhi * 8);
      vb[2 * j] = p[0];
      vb[2 * j + 1] = p[4];
    }

#pragma unroll
    for (int f = 0; f < 2; ++f) {
      // ---- swapped QK^T: C[key][q], q = llo lane-local ----
      f32x4 s[4];
      __builtin_amdgcn_s_setprio(1);
#pragma unroll
      for (int j = 0; j < 4; ++j) {
        s[j] = mfma16(kb[2 * j], qa[f][0], f32x4{0.f, 0.f, 0.f, 0.f});
        s[j] = mfma16(kb[2 * j + 1], qa[f][1], s[j]);
      }
      __builtin_amdgcn_s_setprio(0);
      if (f == 1 && t < t1) loadK(t + 1);  // prefetch under softmax+PV

      const int q = wq0 + f * 16 + llo;
      if (!interior) {
#pragma unroll
        for (int j = 0; j < 4; ++j)
#pragma unroll
          for (int r = 0; r < 4; ++r) {
            int key = k0 + j * 16 + lhi * 4 + r;
            s[j][r] = (key <= q && key >= q - (WIN_ - 1)) ? s[j][r] : -1e30f;
          }
      }
      // ---- lane-local tree max over this lane's 16 keys ----
      float mj0 = fmaxf(fmaxf(s[0][0], s[0][1]), fmaxf(s[0][2], s[0][3]));
      float mj1 = fmaxf(fmaxf(s[1][0], s[1][1]), fmaxf(s[1][2], s[1][3]));
      float mj2 = fmaxf(fmaxf(s[2][0], s[2][1]), fmaxf(s[2][2], s[2][3]));
      float mj3 = fmaxf(fmaxf(s[3][0], s[3][1]), fmaxf(s[3][2], s[3][3]));
      float lmax = fmaxf(fmaxf(mj0, mj1), fmaxf(mj2, mj3));

      // ---- defer-max: common path needs NO cross-lane ops ----
      if (!__all(lmax <= m_q[f] + 11.0f)) {   // rare: running max grew
        float m1 = lmax;
        m1 = fmaxf(m1, __shfl_xor(m1, 16));
        m1 = fmaxf(m1, __shfl_xor(m1, 32));
        float mnew = fmaxf(m_q[f], m1);
        float alpha = __builtin_amdgcn_exp2f(m_q[f] - mnew);
        m_q[f] = mnew;
        l_q[f] *= alpha;                      // lane-partial, alpha quad-uniform
#pragma unroll
        for (int r = 0; r < 4; ++r) {         // redistribute alpha to ctx rows
          float ar = __shfl(alpha, (lane & 48) | (lhi * 4 + r));
#pragma unroll
          for (int j = 0; j < 4; ++j) ctxa[f][j][r] *= ar;
        }
      }

      // ---- P = exp2(s - m), lane-partial sum ----
      float pv[4][4];
#pragma unroll
      for (int j = 0; j < 4; ++j)
#pragma unroll
        for (int r = 0; r < 4; ++r) pv[j][r] = __builtin_amdgcn_exp2f(s[j][r] - m_q[f]);
      float s0 = (pv[0][0] + pv[0][1]) + (pv[0][2] + pv[0][3]);
      float s1 = (pv[1][0] + pv[1][1]) + (pv[1][2] + pv[1][3]);
      float s2 = (pv[2][0] + pv[2][1]) + (pv[2][2] + pv[2][3]);
      float s3 = (pv[3][0] + pv[3][1]) + (pv[3][2] + pv[3][3]);
      l_q[f] += (s0 + s1) + (s2 + s3);

      // ---- P -> wave-private LDS (vector b64 stores, swizzled) ----
      char* rowb = lpw + (f * 16 + llo) * 128;
#pragma unroll
      for (int j = 0; j < 4; ++j) {
        us4 pk;
        pk[0] = f2bf(pv[j][0]); pk[1] = f2bf(pv[j][1]);
        pk[2] = f2bf(pv[j][2]); pk[3] = f2bf(pv[j][3]);
        int swc = (2 * j + (lhi >> 1)) ^ psw;
        *(us4*)(rowb + swc * 16 + (lhi & 1) * 8) = pk;
      }
    }

    // ---- P back as A-frag (row=q=llo, k=keys lhi*8+e); f0 write latency hidden ----
    short8 pa[2][2];
#pragma unroll
    for (int f = 0; f < 2; ++f) {
      char* rowb = lpw + (f * 16 + llo) * 128;
      pa[f][0] = *(const short8*)(rowb + ((lhi ^ psw) << 4));
      pa[f][1] = *(const short8*)(rowb + (((lhi + 4) ^ psw) << 4));
    }

    // ---- PV: ctx[q][dim] += P * V ----
    __builtin_amdgcn_s_setprio(1);
#pragma unroll
    for (int j = 0; j < 4; ++j) {
      ctxa[0][j] = mfma16(pa[0][0], vb[2 * j], ctxa[0][j]);
      ctxa[0][j] = mfma16(pa[0][1], vb[2 * j + 1], ctxa[0][j]);
      ctxa[1][j] = mfma16(pa[1][0], vb[2 * j], ctxa[1][j]);
      ctxa[1][j] = mfma16(pa[1][1], vb[2 * j + 1], ctxa[1][j]);
    }
    __builtin_amdgcn_s_setprio(0);
  }

  const int b = bh >> 4, h = bh & 15;
#pragma unroll
  for (int f = 0; f < 2; ++f) {
    float lt = l_q[f];                       // reduce lane-partial denom (epilogue only)
    lt += __shfl_xor(lt, 16);
    lt += __shfl_xor(lt, 32);
    float li = 1.0f / lt;
#pragma unroll
    for (int r = 0; r < 4; ++r) {
      float linv = __shfl(li, (lane & 48) | (lhi * 4 + r));
      int qrow = wq0 + f * 16 + lhi * 4 + r;
      size_t base = ((size_t)b * L_ + qrow) * DM_ + h * DH_;
#pragma unroll
      for (int j = 0; j < 4; ++j)
        __builtin_nontemporal_store(f2bf(ctxa[f][j][r] * linv), &CTX[base + j * 16 + llo]);
    }
  }
}

// ---------------- launch ----------------
extern "C" void kernel_launch(void* const* d_in, const int* in_sizes, int n_in,
                              void* d_out, int out_size, void* d_ws, size_t ws_size,
                              hipStream_t stream) {
  (void)in_sizes; (void)n_in; (void)out_size; (void)ws_size;
  const float* x    = (const float*)d_in[0];
  // d_in[1] = attn_mask (all ones) -- unused
  const float* wqkv = (const float*)d_in[2];
  const float* wout = (const float*)d_in[3];
  float* out = (float*)d_out;

  char* w = (char*)d_ws;
  unsigned short* X   = (unsigned short*)(w);                         // 16MB (aliased by CTX)
  unsigned short* WQT = (unsigned short*)(w + 16777216);              // 6MB
  unsigned short* POT = (unsigned short*)(w + 23068672);              // 2MB
  float*          COS = (float*)(w + 25165824);                       // 128KB
  float*          SIN = (float*)(w + 25296896);                       // 128KB
  unsigned short* Qb  = (unsigned short*)(w + 25427968);              // 16MB
  unsigned short* Kb  = (unsigned short*)(w + 25427968 + 16777216);   // 16MB
  unsigned short* VTb = (unsigned short*)(w + 25427968 + 2*16777216); // 16MB (direct from qkv)
  unsigned short* CTX = X;   // x dead after k_gemm_qkv; reuse for ctx

  k_cvt<<<dim3(8192), dim3(256), 0, stream>>>(x, X, M_ * DM_);
  k_wt<<<dim3(96, 32), dim3(256), 0, stream>>>(wqkv, WQT, 3072);
  k_wt<<<dim3(32, 32), dim3(256), 0, stream>>>(wout, POT, 1024);
  k_rope<<<dim3(128), dim3(256), 0, stream>>>(COS, SIN);
  k_gemm_qkv<<<dim3(1536), dim3(256), 0, stream>>>(X, WQT, Qb, Kb, VTb, COS, SIN);
  k_attn<<<dim3(64, 16), dim3(256), 0, stream>>>(Qb, Kb, VTb, CTX);
  k_gemm_out<<<dim3(512), dim3(256), 0, stream>>>(CTX, POT, out);
}

// Round 10
// 184.607 us; speedup vs baseline: 1.7572x; 1.7572x over previous
//
#include <hip/hip_runtime.h>
#include <hip/hip_bf16.h>
#include <stdint.h>

#define B_    4
#define L_    2048
#define H_    16
#define DH_   64
#define DM_   1024
#define M_    8192
#define WIN_  512

typedef short  short8 __attribute__((ext_vector_type(8)));
typedef __bf16 bf16x8 __attribute__((ext_vector_type(8)));
typedef float  f32x4  __attribute__((ext_vector_type(4)));
typedef unsigned short us4 __attribute__((ext_vector_type(4)));

__device__ __forceinline__ unsigned short f2bf(float f) {
  return __builtin_bit_cast(unsigned short, __float2bfloat16(f));
}
__device__ __forceinline__ f32x4 mfma16(short8 a, short8 b, f32x4 c) {
  return __builtin_amdgcn_mfma_f32_16x16x32_bf16(
      __builtin_bit_cast(bf16x8, a), __builtin_bit_cast(bf16x8, b), c, 0, 0, 0);
}
__device__ __forceinline__ void async16(const void* g, void* lds) {
  __builtin_amdgcn_global_load_lds(
      (const __attribute__((address_space(1))) void*)g,
      (__attribute__((address_space(3))) void*)lds, 16, 0, 0);
}
template<int N> __device__ __forceinline__ void vmwait() {
  if constexpr (N == 4)      asm volatile("s_waitcnt vmcnt(4)" ::: "memory");
  else                       asm volatile("s_waitcnt vmcnt(0)" ::: "memory");
}

// ---------------- kernel 0a: fp32 -> bf16 convert ----------------
__global__ __launch_bounds__(256) void k_cvt(const float* __restrict__ in,
                                             unsigned short* __restrict__ out, int n) {
  int idx = (blockIdx.x * 256 + threadIdx.x) * 4;
  if (idx >= n) return;
  float4 f = *(const float4*)(in + idx);
  us4 o;
  o[0] = f2bf(f.x); o[1] = f2bf(f.y); o[2] = f2bf(f.z); o[3] = f2bf(f.w);
  *(us4*)(out + idx) = o;
}

// ---------- kernel 0b: convert + transpose W (Kdim x N_) -> (N_ x Kdim) bf16 ----------
__global__ __launch_bounds__(256) void k_wt(const float* __restrict__ W,
                                            unsigned short* __restrict__ WT, int N_) {
  __shared__ unsigned short t[32][33];
  int n0 = blockIdx.x * 32, k0 = blockIdx.y * 32;
  int tid = threadIdx.x;
  int r = tid >> 3, c4 = (tid & 7) * 4;
  float4 f = *(const float4*)(W + (size_t)(k0 + r) * N_ + n0 + c4);
  t[r][c4 + 0] = f2bf(f.x); t[r][c4 + 1] = f2bf(f.y);
  t[r][c4 + 2] = f2bf(f.z); t[r][c4 + 3] = f2bf(f.w);
  __syncthreads();
  unsigned short* dst = WT + (size_t)(n0 + r) * 1024 + k0 + c4;
  dst[0] = t[c4 + 0][r]; dst[1] = t[c4 + 1][r];
  dst[2] = t[c4 + 2][r]; dst[3] = t[c4 + 3][r];
}

// ---------------- kernel 0d: rotary tables cos/sin [L_][16] ----------------
__global__ __launch_bounds__(256) void k_rope(float* __restrict__ C, float* __restrict__ S) {
  int idx = blockIdx.x * 256 + threadIdx.x;   // 0..32767
  int tpos = idx >> 4, fi = idx & 15;
  float freq = 1.0f / powf(10000.0f, (float)fi / 16.0f);
  float a = (float)tpos * freq;
  C[idx] = cosf(a);
  S[idx] = sinf(a);
}

// ======== 128x128 triple-buffered MFMA GEMM core (K=1024, BK=32) ========
// Linear grid, m fastest: default XCD round-robin keeps a 2MB A-stripe/XCD L2.
__device__ __forceinline__ void gemm128(const unsigned short* __restrict__ A,
                                        const unsigned short* __restrict__ Bt,
                                        int m0, int n0, unsigned short* lds,
                                        f32x4 (&acc)[4][4]) {
  constexpr int SLOT = 8192;                    // (128+128)*32 elements
  const int tid = threadIdx.x, lane = tid & 63;
  const int wave = tid >> 6, wn = wave & 1, wm = wave >> 1;
  const int llo = lane & 15, lhi = lane >> 4;
  const int swz = (llo >> 1) & 3;
  const int rbase = wm * 64, cbase = wn * 64;

  auto stage = [&](int t) {
    unsigned short* s = lds + (t % 3) * SLOT;
    const int kt = t * 32;
#pragma unroll
    for (int i = 0; i < 2; ++i) {               // A: 512 16B-chunks
      int q = i * 256 + tid;
      int row = q >> 2, cs = (q & 3) ^ ((row >> 1) & 3);
      async16(A + (size_t)(m0 + row) * DM_ + kt + cs * 8, s + q * 8);
    }
#pragma unroll
    for (int i = 0; i < 2; ++i) {               // B: 512 16B-chunks
      int q = i * 256 + tid;
      int row = q >> 2, cs = (q & 3) ^ ((row >> 1) & 3);
      async16(Bt + (size_t)(n0 + row) * DM_ + kt + cs * 8, s + 4096 + q * 8);
    }
  };

  stage(0); stage(1);
#pragma unroll 4
  for (int t = 0; t < 32; ++t) {
    if (t < 31) vmwait<4>(); else vmwait<0>();  // tile t landed; t+1 stays in flight
    __builtin_amdgcn_s_barrier();               // all waves done reading tile t-1
    if (t + 2 < 32) stage(t + 2);               // overwrites slot (t-1)%3 - safe
    const unsigned short* sa = lds + (t % 3) * SLOT;
    const unsigned short* sb = sa + 4096;
    short8 af[4], bf[4];
#pragma unroll
    for (int i = 0; i < 4; ++i)
      af[i] = *(const short8*)(sa + (rbase + i * 16 + llo) * 32 + ((lhi ^ swz) << 3));
#pragma unroll
    for (int j = 0; j < 4; ++j)
      bf[j] = *(const short8*)(sb + (cbase + j * 16 + llo) * 32 + ((lhi ^ swz) << 3));
    __builtin_amdgcn_s_setprio(1);
#pragma unroll
    for (int i = 0; i < 4; ++i)
#pragma unroll
      for (int j = 0; j < 4; ++j)
        acc[i][j] = mfma16(af[i], bf[j], acc[i][j]);
    __builtin_amdgcn_s_setprio(0);
  }
}

// ---------------- kernel 1: qkv GEMM + rotary epilogue (128x128 tile) ----------------
__global__ __launch_bounds__(256, 3) void k_gemm_qkv(const unsigned short* __restrict__ X,
                                                     const unsigned short* __restrict__ WT,
                                                     unsigned short* __restrict__ Q,
                                                     unsigned short* __restrict__ Kq,
                                                     unsigned short* __restrict__ V,
                                                     const float* __restrict__ COS,
                                                     const float* __restrict__ SIN) {
  __shared__ unsigned short lds[3 * 8192];   // 48 KiB
  const int wgid = blockIdx.x;               // linear, m fastest (see gemm128 note)
  const int m0 = (wgid & 63) * 128, n0 = (wgid >> 6) * 128;
  f32x4 acc[4][4];
#pragma unroll
  for (int i = 0; i < 4; ++i)
#pragma unroll
    for (int j = 0; j < 4; ++j) acc[i][j] = f32x4{0.f, 0.f, 0.f, 0.f};

  gemm128(X, WT, m0, n0, lds, acc);

  const int tid = threadIdx.x, lane = tid & 63;
  const int wave = tid >> 6, wn = wave & 1, wm = wave >> 1;
  const int llo = lane & 15, lhi = lane >> 4;
  const int ncol = n0 + wn * 64;         // one 64-col head-section per wave
  const int sec = ncol >> 10;            // 0=q 1=k 2=v
  const int h = (ncol & 1023) >> 6;
  unsigned short* dst = (sec == 0) ? Q : (sec == 1 ? Kq : V);
  const bool rot = (sec < 2);
  // Q prescale: 0.125 (softmax scale) * log2(e) -> scores land in log2 domain
  const float qs = (sec == 0) ? 0.18033688f : 1.0f;
#pragma unroll
  for (int i = 0; i < 4; ++i) {
#pragma unroll
    for (int r = 0; r < 4; ++r) {
      int m = m0 + wm * 64 + i * 16 + lhi * 4 + r;     // global token
      int b = m >> 11, l = m & 2047;
      float c0 = acc[i][0][r], c1 = acc[i][1][r];
      float c2 = acc[i][2][r], c3 = acc[i][3][r];
      if (rot) {
        float cs = COS[l * 16 + llo], sn = SIN[l * 16 + llo];
        float n0v = c0 * cs - c1 * sn;
        float n1v = c1 * cs + c0 * sn;
        c0 = n0v; c1 = n1v;
      }
      c0 *= qs; c1 *= qs; c2 *= qs; c3 *= qs;
      size_t base = ((size_t)(b * H_ + h) * L_ + l) * DH_;
      dst[base +      llo] = f2bf(c0);
      dst[base + 16 + llo] = f2bf(c1);
      dst[base + 32 + llo] = f2bf(c2);
      dst[base + 48 + llo] = f2bf(c3);
    }
  }
}

// ---------------- kernel 4: out GEMM (128x128 tile, fp32 epilogue) ----------------
__global__ __launch_bounds__(256, 3) void k_gemm_out(const unsigned short* __restrict__ A,
                                                     const unsigned short* __restrict__ WT,
                                                     float* __restrict__ Cout) {
  __shared__ unsigned short lds[3 * 8192];   // 48 KiB
  const int wgid = blockIdx.x;               // linear, m fastest
  const int m0 = (wgid & 63) * 128, n0 = (wgid >> 6) * 128;
  f32x4 acc[4][4];
#pragma unroll
  for (int i = 0; i < 4; ++i)
#pragma unroll
    for (int j = 0; j < 4; ++j) acc[i][j] = f32x4{0.f, 0.f, 0.f, 0.f};

  gemm128(A, WT, m0, n0, lds, acc);

  const int tid = threadIdx.x, lane = tid & 63;
  const int wave = tid >> 6, wn = wave & 1, wm = wave >> 1;
  const int llo = lane & 15, lhi = lane >> 4;
#pragma unroll
  for (int i = 0; i < 4; ++i)
#pragma unroll
    for (int r = 0; r < 4; ++r) {
      int m = m0 + wm * 64 + i * 16 + lhi * 4 + r;
#pragma unroll
      for (int j = 0; j < 4; ++j)
        Cout[(size_t)m * DM_ + n0 + wn * 64 + j * 16 + llo] = acc[i][j][r];
    }
}

// ---------------- kernel 2: V (B,H,L,64) -> VT (B,H,64,L) ----------------
__global__ __launch_bounds__(256) void k_vt(const unsigned short* __restrict__ V,
                                            unsigned short* __restrict__ VT) {
  __shared__ unsigned short t[64][65];
  int l0 = blockIdx.x * 64, bh = blockIdx.y;
  int tid = threadIdx.x;
  int r = tid >> 2, c = (tid & 3) * 16;
  const unsigned short* src = V + ((size_t)bh * L_ + l0 + r) * DH_ + c;
#pragma unroll
  for (int k = 0; k < 16; ++k) t[r][c + k] = src[k];
  __syncthreads();
  unsigned short* dst = VT + ((size_t)bh * DH_ + r) * L_ + l0 + c;
#pragma unroll
  for (int k = 0; k < 16; ++k) dst[k] = t[c + k][r];
}

// ---------------- kernel 3: barrier-free direct-L2 flash attention ----------------
// Wave = 64 q-rows (4 fragments), independent; 2 blocks/CU (L2-safe residency,
// round-9 lesson: 4/CU thrashes the 4MB/XCD K+V working set). Swapped QK^T,
// log2-domain defer-max softmax: common path has zero cross-lane ops. The 4
// independent fragment chains supply the ILP that block-residency can't.
__global__ __launch_bounds__(256, 2) void k_attn(const unsigned short* __restrict__ Q,
                                                 const unsigned short* __restrict__ Kg,
                                                 const unsigned short* __restrict__ VT,
                                                 unsigned short* __restrict__ CTX) {
  __shared__ unsigned short lp[4][4096];   // per-wave P: 64 rows x 64 keys, swizzled
  const int tid = threadIdx.x, wave = tid >> 6, lane = tid & 63;
  const int bh = blockIdx.x;
  const int qs = 7 - blockIdx.y;           // heavy (long-window) blocks dispatch first
  const int wq0 = qs * 256 + wave * 64;
  const int llo = lane & 15, lhi = lane >> 4;

  // Q as B-fragment (prescaled by 0.125*log2e in qkv epilogue)
  short8 qa[4][2];
#pragma unroll
  for (int f = 0; f < 4; ++f) {
    const short8* qp = (const short8*)(Q + ((size_t)bh * L_ + wq0 + f * 16 + llo) * DH_ + lhi * 8);
    qa[f][0] = __builtin_nontemporal_load(qp);
    qa[f][1] = __builtin_nontemporal_load(qp + 4);
  }

  f32x4 ctxa[4][4];
#pragma unroll
  for (int f = 0; f < 4; ++f)
#pragma unroll
    for (int j = 0; j < 4; ++j) ctxa[f][j] = f32x4{0.f, 0.f, 0.f, 0.f};
  float m_q[4] = {-1e30f, -1e30f, -1e30f, -1e30f};   // running max (log2), quad-uniform
  float l_q[4] = {0.f, 0.f, 0.f, 0.f};               // lane-PARTIAL denom

  const int t0 = (wq0 > (WIN_ - 1) ? wq0 - (WIN_ - 1) : 0) >> 6;
  const int t1 = (wq0 + 63) >> 6;
  const unsigned short* Kb_ = Kg + (size_t)bh * L_ * DH_;
  const unsigned short* Vb_ = VT + (size_t)bh * DH_ * L_;
  char* lpw = (char*)lp[wave];
  const int psw = (llo & 7);               // P swizzle key (row-derived)

  short8 kb[8];                            // K A-frag: row=key(k0+j*16+llo), k=dim lhi*8+e
  auto loadK = [&](int t) {
    const int k0 = t * 64;
#pragma unroll
    for (int j = 0; j < 4; ++j) {
      const short8* p = (const short8*)(Kb_ + (size_t)(k0 + j * 16 + llo) * DH_ + lhi * 8);
      kb[2 * j] = p[0];
      kb[2 * j + 1] = p[4];
    }
  };
  loadK(t0);

  for (int t = t0; t <= t1; ++t) {
    const int k0 = t * 64;
    const bool interior = (k0 + 63 <= wq0) && (k0 >= wq0 - (WIN_ - 64));
    // V B-frag loads (needed after softmax, latency hidden under QK+softmax)
    short8 vb[8];
#pragma unroll
    for (int j = 0; j < 4; ++j) {
      const short8* p = (const short8*)(Vb_ + (size_t)(j * 16 + llo) * L_ + k0 + lhi * 8);
      vb[2 * j] = p[0];
      vb[2 * j + 1] = p[4];
    }

#pragma unroll
    for (int f = 0; f < 4; ++f) {
      // ---- swapped QK^T: C[key][q], q = llo lane-local ----
      f32x4 s[4];
      __builtin_amdgcn_s_setprio(1);
#pragma unroll
      for (int j = 0; j < 4; ++j) {
        s[j] = mfma16(kb[2 * j], qa[f][0], f32x4{0.f, 0.f, 0.f, 0.f});
        s[j] = mfma16(kb[2 * j + 1], qa[f][1], s[j]);
      }
      __builtin_amdgcn_s_setprio(0);
      if (f == 3 && t < t1) loadK(t + 1);  // prefetch under remaining softmax+PV

      const int q = wq0 + f * 16 + llo;
      if (!interior) {
#pragma unroll
        for (int j = 0; j < 4; ++j)
#pragma unroll
          for (int r = 0; r < 4; ++r) {
            int key = k0 + j * 16 + lhi * 4 + r;
            s[j][r] = (key <= q && key >= q - (WIN_ - 1)) ? s[j][r] : -1e30f;
          }
      }
      // ---- lane-local tree max over this lane's 16 keys ----
      float mj0 = fmaxf(fmaxf(s[0][0], s[0][1]), fmaxf(s[0][2], s[0][3]));
      float mj1 = fmaxf(fmaxf(s[1][0], s[1][1]), fmaxf(s[1][2], s[1][3]));
      float mj2 = fmaxf(fmaxf(s[2][0], s[2][1]), fmaxf(s[2][2], s[2][3]));
      float mj3 = fmaxf(fmaxf(s[3][0], s[3][1]), fmaxf(s[3][2], s[3][3]));
      float lmax = fmaxf(fmaxf(mj0, mj1), fmaxf(mj2, mj3));

      // ---- defer-max: common path needs NO cross-lane ops ----
      if (!__all(lmax <= m_q[f] + 11.0f)) {   // rare: running max grew
        float m1 = lmax;
        m1 = fmaxf(m1, __shfl_xor(m1, 16));
        m1 = fmaxf(m1, __shfl_xor(m1, 32));
        float mnew = fmaxf(m_q[f], m1);
        float alpha = __builtin_amdgcn_exp2f(m_q[f] - mnew);
        m_q[f] = mnew;
        l_q[f] *= alpha;                      // lane-partial, alpha quad-uniform
#pragma unroll
        for (int r = 0; r < 4; ++r) {         // redistribute alpha to ctx rows
          float ar = __shfl(alpha, (lane & 48) | (lhi * 4 + r));
#pragma unroll
          for (int j = 0; j < 4; ++j) ctxa[f][j][r] *= ar;
        }
      }

      // ---- P = exp2(s - m), lane-partial sum ----
      float pv[4][4];
#pragma unroll
      for (int j = 0; j < 4; ++j)
#pragma unroll
        for (int r = 0; r < 4; ++r) pv[j][r] = __builtin_amdgcn_exp2f(s[j][r] - m_q[f]);
      float s0 = (pv[0][0] + pv[0][1]) + (pv[0][2] + pv[0][3]);
      float s1 = (pv[1][0] + pv[1][1]) + (pv[1][2] + pv[1][3]);
      float s2 = (pv[2][0] + pv[2][1]) + (pv[2][2] + pv[2][3]);
      float s3 = (pv[3][0] + pv[3][1]) + (pv[3][2] + pv[3][3]);
      l_q[f] += (s0 + s1) + (s2 + s3);

      // ---- P -> wave-private LDS (vector b64 stores, swizzled) ----
      char* rowb = lpw + (f * 16 + llo) * 128;
#pragma unroll
      for (int j = 0; j < 4; ++j) {
        us4 pk;
        pk[0] = f2bf(pv[j][0]); pk[1] = f2bf(pv[j][1]);
        pk[2] = f2bf(pv[j][2]); pk[3] = f2bf(pv[j][3]);
        int swc = (2 * j + (lhi >> 1)) ^ psw;
        *(us4*)(rowb + swc * 16 + (lhi & 1) * 8) = pk;
      }
    }

    // ---- P back as A-frag (row=q=llo, k=keys lhi*8+e); write latency hidden ----
    short8 pa[4][2];
#pragma unroll
    for (int f = 0; f < 4; ++f) {
      char* rowb = lpw + (f * 16 + llo) * 128;
      pa[f][0] = *(const short8*)(rowb + ((lhi ^ psw) << 4));
      pa[f][1] = *(const short8*)(rowb + (((lhi + 4) ^ psw) << 4));
    }

    // ---- PV: ctx[q][dim] += P * V (V fragments shared across 4 frags) ----
    __builtin_amdgcn_s_setprio(1);
#pragma unroll
    for (int j = 0; j < 4; ++j) {
#pragma unroll
      for (int f = 0; f < 4; ++f) {
        ctxa[f][j] = mfma16(pa[f][0], vb[2 * j], ctxa[f][j]);
        ctxa[f][j] = mfma16(pa[f][1], vb[2 * j + 1], ctxa[f][j]);
      }
    }
    __builtin_amdgcn_s_setprio(0);
  }

  const int b = bh >> 4, h = bh & 15;
#pragma unroll
  for (int f = 0; f < 4; ++f) {
    float lt = l_q[f];                       // reduce lane-partial denom (epilogue only)
    lt += __shfl_xor(lt, 16);
    lt += __shfl_xor(lt, 32);
    float li = 1.0f / lt;
#pragma unroll
    for (int r = 0; r < 4; ++r) {
      float linv = __shfl(li, (lane & 48) | (lhi * 4 + r));
      int qrow = wq0 + f * 16 + lhi * 4 + r;
      size_t base = ((size_t)b * L_ + qrow) * DM_ + h * DH_;
#pragma unroll
      for (int j = 0; j < 4; ++j)
        __builtin_nontemporal_store(f2bf(ctxa[f][j][r] * linv), &CTX[base + j * 16 + llo]);
    }
  }
}

// ---------------- launch ----------------
extern "C" void kernel_launch(void* const* d_in, const int* in_sizes, int n_in,
                              void* d_out, int out_size, void* d_ws, size_t ws_size,
                              hipStream_t stream) {
  (void)in_sizes; (void)n_in; (void)out_size; (void)ws_size;
  const float* x    = (const float*)d_in[0];
  // d_in[1] = attn_mask (all ones) -- unused
  const float* wqkv = (const float*)d_in[2];
  const float* wout = (const float*)d_in[3];
  float* out = (float*)d_out;

  char* w = (char*)d_ws;
  unsigned short* X   = (unsigned short*)(w);                         // 16MB (aliased by CTX)
  unsigned short* WQT = (unsigned short*)(w + 16777216);              // 6MB
  unsigned short* POT = (unsigned short*)(w + 23068672);              // 2MB
  float*          COS = (float*)(w + 25165824);                       // 128KB
  float*          SIN = (float*)(w + 25296896);                       // 128KB
  unsigned short* Qb  = (unsigned short*)(w + 25427968);              // 16MB
  unsigned short* Kb  = (unsigned short*)(w + 25427968 + 16777216);   // 16MB
  unsigned short* Vb  = (unsigned short*)(w + 25427968 + 2*16777216); // 16MB
  unsigned short* VTb = (unsigned short*)(w + 25427968 + 3*16777216); // 16MB
  unsigned short* CTX = X;   // x dead after k_gemm_qkv; reuse for ctx

  k_cvt<<<dim3(8192), dim3(256), 0, stream>>>(x, X, M_ * DM_);
  k_wt<<<dim3(96, 32), dim3(256), 0, stream>>>(wqkv, WQT, 3072);
  k_wt<<<dim3(32, 32), dim3(256), 0, stream>>>(wout, POT, 1024);
  k_rope<<<dim3(128), dim3(256), 0, stream>>>(COS, SIN);
  k_gemm_qkv<<<dim3(1536), dim3(256), 0, stream>>>(X, WQT, Qb, Kb, Vb, COS, SIN);
  k_vt<<<dim3(32, 64), dim3(256), 0, stream>>>(Vb, VTb);
  k_attn<<<dim3(64, 8), dim3(256), 0, stream>>>(Qb, Kb, VTb, CTX);
  k_gemm_out<<<dim3(512), dim3(256), 0, stream>>>(CTX, POT, out);
}

// Round 11
// 166.925 us; speedup vs baseline: 1.9433x; 1.1059x over previous
//
#include <hip/hip_runtime.h>
#include <hip/hip_bf16.h>
#include <stdint.h>

#define B_    4
#define L_    2048
#define H_    16
#define DH_   64
#define DM_   1024
#define M_    8192
#define WIN_  512

typedef short  short8 __attribute__((ext_vector_type(8)));
typedef __bf16 bf16x8 __attribute__((ext_vector_type(8)));
typedef float  f32x4  __attribute__((ext_vector_type(4)));
typedef unsigned short us4 __attribute__((ext_vector_type(4)));

__device__ __forceinline__ unsigned short f2bf(float f) {
  return __builtin_bit_cast(unsigned short, __float2bfloat16(f));
}
__device__ __forceinline__ f32x4 mfma16(short8 a, short8 b, f32x4 c) {
  return __builtin_amdgcn_mfma_f32_16x16x32_bf16(
      __builtin_bit_cast(bf16x8, a), __builtin_bit_cast(bf16x8, b), c, 0, 0, 0);
}
__device__ __forceinline__ void async16(const void* g, void* lds) {
  __builtin_amdgcn_global_load_lds(
      (const __attribute__((address_space(1))) void*)g,
      (__attribute__((address_space(3))) void*)lds, 16, 0, 0);
}
template<int N> __device__ __forceinline__ void vmwait() {
  if constexpr (N == 4)      asm volatile("s_waitcnt vmcnt(4)" ::: "memory");
  else                       asm volatile("s_waitcnt vmcnt(0)" ::: "memory");
}

// ---------------- kernel 0a: fp32 -> bf16 convert ----------------
__global__ __launch_bounds__(256) void k_cvt(const float* __restrict__ in,
                                             unsigned short* __restrict__ out, int n) {
  int idx = (blockIdx.x * 256 + threadIdx.x) * 4;
  if (idx >= n) return;
  float4 f = *(const float4*)(in + idx);
  us4 o;
  o[0] = f2bf(f.x); o[1] = f2bf(f.y); o[2] = f2bf(f.z); o[3] = f2bf(f.w);
  *(us4*)(out + idx) = o;
}

// ---------- kernel 0b: convert + transpose W (Kdim x N_) -> (N_ x Kdim) bf16 ----------
__global__ __launch_bounds__(256) void k_wt(const float* __restrict__ W,
                                            unsigned short* __restrict__ WT, int N_) {
  __shared__ unsigned short t[32][33];
  int n0 = blockIdx.x * 32, k0 = blockIdx.y * 32;
  int tid = threadIdx.x;
  int r = tid >> 3, c4 = (tid & 7) * 4;
  float4 f = *(const float4*)(W + (size_t)(k0 + r) * N_ + n0 + c4);
  t[r][c4 + 0] = f2bf(f.x); t[r][c4 + 1] = f2bf(f.y);
  t[r][c4 + 2] = f2bf(f.z); t[r][c4 + 3] = f2bf(f.w);
  __syncthreads();
  unsigned short* dst = WT + (size_t)(n0 + r) * 1024 + k0 + c4;
  dst[0] = t[c4 + 0][r]; dst[1] = t[c4 + 1][r];
  dst[2] = t[c4 + 2][r]; dst[3] = t[c4 + 3][r];
}

// ---------------- kernel 0d: rotary tables cos/sin [L_][16] ----------------
__global__ __launch_bounds__(256) void k_rope(float* __restrict__ C, float* __restrict__ S) {
  int idx = blockIdx.x * 256 + threadIdx.x;   // 0..32767
  int tpos = idx >> 4, fi = idx & 15;
  float freq = 1.0f / powf(10000.0f, (float)fi / 16.0f);
  float a = (float)tpos * freq;
  C[idx] = cosf(a);
  S[idx] = sinf(a);
}

// ======== 128x128 triple-buffered MFMA GEMM core (K=1024, BK=32) ========
// Linear grid, m fastest: default XCD round-robin keeps a 2MB A-stripe/XCD L2.
__device__ __forceinline__ void gemm128(const unsigned short* __restrict__ A,
                                        const unsigned short* __restrict__ Bt,
                                        int m0, int n0, unsigned short* lds,
                                        f32x4 (&acc)[4][4]) {
  constexpr int SLOT = 8192;                    // (128+128)*32 elements
  const int tid = threadIdx.x, lane = tid & 63;
  const int wave = tid >> 6, wn = wave & 1, wm = wave >> 1;
  const int llo = lane & 15, lhi = lane >> 4;
  const int swz = (llo >> 1) & 3;
  const int rbase = wm * 64, cbase = wn * 64;

  auto stage = [&](int t) {
    unsigned short* s = lds + (t % 3) * SLOT;
    const int kt = t * 32;
#pragma unroll
    for (int i = 0; i < 2; ++i) {               // A: 512 16B-chunks
      int q = i * 256 + tid;
      int row = q >> 2, cs = (q & 3) ^ ((row >> 1) & 3);
      async16(A + (size_t)(m0 + row) * DM_ + kt + cs * 8, s + q * 8);
    }
#pragma unroll
    for (int i = 0; i < 2; ++i) {               // B: 512 16B-chunks
      int q = i * 256 + tid;
      int row = q >> 2, cs = (q & 3) ^ ((row >> 1) & 3);
      async16(Bt + (size_t)(n0 + row) * DM_ + kt + cs * 8, s + 4096 + q * 8);
    }
  };

  stage(0); stage(1);
#pragma unroll 4
  for (int t = 0; t < 32; ++t) {
    if (t < 31) vmwait<4>(); else vmwait<0>();  // tile t landed; t+1 stays in flight
    __builtin_amdgcn_s_barrier();               // all waves done reading tile t-1
    if (t + 2 < 32) stage(t + 2);               // overwrites slot (t-1)%3 - safe
    const unsigned short* sa = lds + (t % 3) * SLOT;
    const unsigned short* sb = sa + 4096;
    short8 af[4], bf[4];
#pragma unroll
    for (int i = 0; i < 4; ++i)
      af[i] = *(const short8*)(sa + (rbase + i * 16 + llo) * 32 + ((lhi ^ swz) << 3));
#pragma unroll
    for (int j = 0; j < 4; ++j)
      bf[j] = *(const short8*)(sb + (cbase + j * 16 + llo) * 32 + ((lhi ^ swz) << 3));
    __builtin_amdgcn_s_setprio(1);
#pragma unroll
    for (int i = 0; i < 4; ++i)
#pragma unroll
      for (int j = 0; j < 4; ++j)
        acc[i][j] = mfma16(af[i], bf[j], acc[i][j]);
    __builtin_amdgcn_s_setprio(0);
  }
}

// ---------------- kernel 1: qkv GEMM + rotary epilogue (128x128 tile) ----------------
__global__ __launch_bounds__(256, 3) void k_gemm_qkv(const unsigned short* __restrict__ X,
                                                     const unsigned short* __restrict__ WT,
                                                     unsigned short* __restrict__ Q,
                                                     unsigned short* __restrict__ Kq,
                                                     unsigned short* __restrict__ V,
                                                     const float* __restrict__ COS,
                                                     const float* __restrict__ SIN) {
  __shared__ unsigned short lds[3 * 8192];   // 48 KiB
  const int wgid = blockIdx.x;               // linear, m fastest (see gemm128 note)
  const int m0 = (wgid & 63) * 128, n0 = (wgid >> 6) * 128;
  f32x4 acc[4][4];
#pragma unroll
  for (int i = 0; i < 4; ++i)
#pragma unroll
    for (int j = 0; j < 4; ++j) acc[i][j] = f32x4{0.f, 0.f, 0.f, 0.f};

  gemm128(X, WT, m0, n0, lds, acc);

  const int tid = threadIdx.x, lane = tid & 63;
  const int wave = tid >> 6, wn = wave & 1, wm = wave >> 1;
  const int llo = lane & 15, lhi = lane >> 4;
  const int ncol = n0 + wn * 64;         // one 64-col head-section per wave
  const int sec = ncol >> 10;            // 0=q 1=k 2=v
  const int h = (ncol & 1023) >> 6;
  unsigned short* dst = (sec == 0) ? Q : (sec == 1 ? Kq : V);
  const bool rot = (sec < 2);
  // Q prescale: 0.125 (softmax scale) * log2(e) -> scores land in log2 domain
  const float qs = (sec == 0) ? 0.18033688f : 1.0f;
#pragma unroll
  for (int i = 0; i < 4; ++i) {
#pragma unroll
    for (int r = 0; r < 4; ++r) {
      int m = m0 + wm * 64 + i * 16 + lhi * 4 + r;     // global token
      int b = m >> 11, l = m & 2047;
      float c0 = acc[i][0][r], c1 = acc[i][1][r];
      float c2 = acc[i][2][r], c3 = acc[i][3][r];
      if (rot) {
        float cs = COS[l * 16 + llo], sn = SIN[l * 16 + llo];
        float n0v = c0 * cs - c1 * sn;
        float n1v = c1 * cs + c0 * sn;
        c0 = n0v; c1 = n1v;
      }
      c0 *= qs; c1 *= qs; c2 *= qs; c3 *= qs;
      size_t base = ((size_t)(b * H_ + h) * L_ + l) * DH_;
      dst[base +      llo] = f2bf(c0);
      dst[base + 16 + llo] = f2bf(c1);
      dst[base + 32 + llo] = f2bf(c2);
      dst[base + 48 + llo] = f2bf(c3);
    }
  }
}

// ---------------- kernel 4: out GEMM (128x128 tile, fp32 epilogue) ----------------
__global__ __launch_bounds__(256, 3) void k_gemm_out(const unsigned short* __restrict__ A,
                                                     const unsigned short* __restrict__ WT,
                                                     float* __restrict__ Cout) {
  __shared__ unsigned short lds[3 * 8192];   // 48 KiB
  const int wgid = blockIdx.x;               // linear, m fastest
  const int m0 = (wgid & 63) * 128, n0 = (wgid >> 6) * 128;
  f32x4 acc[4][4];
#pragma unroll
  for (int i = 0; i < 4; ++i)
#pragma unroll
    for (int j = 0; j < 4; ++j) acc[i][j] = f32x4{0.f, 0.f, 0.f, 0.f};

  gemm128(A, WT, m0, n0, lds, acc);

  const int tid = threadIdx.x, lane = tid & 63;
  const int wave = tid >> 6, wn = wave & 1, wm = wave >> 1;
  const int llo = lane & 15, lhi = lane >> 4;
#pragma unroll
  for (int i = 0; i < 4; ++i)
#pragma unroll
    for (int r = 0; r < 4; ++r) {
      int m = m0 + wm * 64 + i * 16 + lhi * 4 + r;
#pragma unroll
      for (int j = 0; j < 4; ++j)
        Cout[(size_t)m * DM_ + n0 + wn * 64 + j * 16 + llo] = acc[i][j][r];
    }
}

// ---------------- kernel 2: V (B,H,L,64) -> VT (B,H,64,L) ----------------
__global__ __launch_bounds__(256) void k_vt(const unsigned short* __restrict__ V,
                                            unsigned short* __restrict__ VT) {
  __shared__ unsigned short t[64][65];
  int l0 = blockIdx.x * 64, bh = blockIdx.y;
  int tid = threadIdx.x;
  int r = tid >> 2, c = (tid & 3) * 16;
  const unsigned short* src = V + ((size_t)bh * L_ + l0 + r) * DH_ + c;
#pragma unroll
  for (int k = 0; k < 16; ++k) t[r][c + k] = src[k];
  __syncthreads();
  unsigned short* dst = VT + ((size_t)bh * DH_ + r) * L_ + l0 + c;
#pragma unroll
  for (int k = 0; k < 16; ++k) dst[k] = t[c + k][r];
}

// ---------------- kernel 3: barrier-free direct-L2 flash attention ----------------
// Wave = 64 q-rows (4 fragments). SPILL-FREE build: amdgpu_waves_per_eu(1,2)
// stops the compiler's occupancy-chase (rounds 7-10 allocated 96-128 VGPR and
// spilled ~10-20MB/dispatch to scratch -- the real latency source). Freed
// budget funds a kb double-buffer: K(t+1) issues at f==0 of tile t (full-tile
// latency hiding, no WAR stall on kb).
__global__ __launch_bounds__(256) __attribute__((amdgpu_waves_per_eu(1, 2)))
void k_attn(const unsigned short* __restrict__ Q,
            const unsigned short* __restrict__ Kg,
            const unsigned short* __restrict__ VT,
            unsigned short* __restrict__ CTX) {
  __shared__ unsigned short lp[4][4096];   // per-wave P: 64 rows x 64 keys, swizzled
  const int tid = threadIdx.x, wave = tid >> 6, lane = tid & 63;
  const int bh = blockIdx.x;
  const int qs = 7 - blockIdx.y;           // heavy (long-window) blocks dispatch first
  const int wq0 = qs * 256 + wave * 64;
  const int llo = lane & 15, lhi = lane >> 4;

  // Q as B-fragment (prescaled by 0.125*log2e in qkv epilogue)
  short8 qa[4][2];
#pragma unroll
  for (int f = 0; f < 4; ++f) {
    const short8* qp = (const short8*)(Q + ((size_t)bh * L_ + wq0 + f * 16 + llo) * DH_ + lhi * 8);
    qa[f][0] = __builtin_nontemporal_load(qp);
    qa[f][1] = __builtin_nontemporal_load(qp + 4);
  }

  f32x4 ctxa[4][4];
#pragma unroll
  for (int f = 0; f < 4; ++f)
#pragma unroll
    for (int j = 0; j < 4; ++j) ctxa[f][j] = f32x4{0.f, 0.f, 0.f, 0.f};
  float m_q[4] = {-1e30f, -1e30f, -1e30f, -1e30f};   // running max (log2), quad-uniform
  float l_q[4] = {0.f, 0.f, 0.f, 0.f};               // lane-PARTIAL denom

  const int t0 = (wq0 > (WIN_ - 1) ? wq0 - (WIN_ - 1) : 0) >> 6;
  const int t1 = (wq0 + 63) >> 6;
  const unsigned short* Kb_ = Kg + (size_t)bh * L_ * DH_;
  const unsigned short* Vb_ = VT + (size_t)bh * DH_ * L_;
  char* lpw = (char*)lp[wave];
  const int psw = (llo & 7);               // P swizzle key (row-derived)

  short8 kbA[8], kbB[8];                   // K A-frag double buffer
  auto loadK = [&](int t, short8* kb) {
    const int k0 = t * 64;
#pragma unroll
    for (int j = 0; j < 4; ++j) {
      const short8* p = (const short8*)(Kb_ + (size_t)(k0 + j * 16 + llo) * DH_ + lhi * 8);
      kb[2 * j] = p[0];
      kb[2 * j + 1] = p[4];
    }
  };
  loadK(t0, kbA);

  for (int t = t0; t <= t1; ++t) {
    const int k0 = t * 64;
    const bool interior = (k0 + 63 <= wq0) && (k0 >= wq0 - (WIN_ - 64));
    // V B-frag loads (used after QK+softmax; ~800 cyc of hiding)
    short8 vb[8];
#pragma unroll
    for (int j = 0; j < 4; ++j) {
      const short8* p = (const short8*)(Vb_ + (size_t)(j * 16 + llo) * L_ + k0 + lhi * 8);
      vb[2 * j] = p[0];
      vb[2 * j + 1] = p[4];
    }

#pragma unroll
    for (int f = 0; f < 4; ++f) {
      // ---- swapped QK^T: C[key][q], q = llo lane-local ----
      f32x4 s[4];
      __builtin_amdgcn_s_setprio(1);
#pragma unroll
      for (int j = 0; j < 4; ++j) {
        s[j] = mfma16(kbA[2 * j], qa[f][0], f32x4{0.f, 0.f, 0.f, 0.f});
        s[j] = mfma16(kbA[2 * j + 1], qa[f][1], s[j]);
      }
      __builtin_amdgcn_s_setprio(0);
      if (f == 0 && t < t1) loadK(t + 1, kbB);  // early issue -> full-tile hiding

      const int q = wq0 + f * 16 + llo;
      if (!interior) {
#pragma unroll
        for (int j = 0; j < 4; ++j)
#pragma unroll
          for (int r = 0; r < 4; ++r) {
            int key = k0 + j * 16 + lhi * 4 + r;
            s[j][r] = (key <= q && key >= q - (WIN_ - 1)) ? s[j][r] : -1e30f;
          }
      }
      // ---- lane-local tree max over this lane's 16 keys ----
      float mj0 = fmaxf(fmaxf(s[0][0], s[0][1]), fmaxf(s[0][2], s[0][3]));
      float mj1 = fmaxf(fmaxf(s[1][0], s[1][1]), fmaxf(s[1][2], s[1][3]));
      float mj2 = fmaxf(fmaxf(s[2][0], s[2][1]), fmaxf(s[2][2], s[2][3]));
      float mj3 = fmaxf(fmaxf(s[3][0], s[3][1]), fmaxf(s[3][2], s[3][3]));
      float lmax = fmaxf(fmaxf(mj0, mj1), fmaxf(mj2, mj3));

      // ---- defer-max: common path needs NO cross-lane ops ----
      if (!__all(lmax <= m_q[f] + 11.0f)) {   // rare: running max grew
        float m1 = lmax;
        m1 = fmaxf(m1, __shfl_xor(m1, 16));
        m1 = fmaxf(m1, __shfl_xor(m1, 32));
        float mnew = fmaxf(m_q[f], m1);
        float alpha = __builtin_amdgcn_exp2f(m_q[f] - mnew);
        m_q[f] = mnew;
        l_q[f] *= alpha;                      // lane-partial, alpha quad-uniform
#pragma unroll
        for (int r = 0; r < 4; ++r) {         // redistribute alpha to ctx rows
          float ar = __shfl(alpha, (lane & 48) | (lhi * 4 + r));
#pragma unroll
          for (int j = 0; j < 4; ++j) ctxa[f][j][r] *= ar;
        }
      }

      // ---- P = exp2(s - m): fused exp2 -> pack -> LDS (short live ranges) ----
      char* rowb = lpw + (f * 16 + llo) * 128;
      float lacc = 0.f;
#pragma unroll
      for (int j = 0; j < 4; ++j) {
        float p0 = __builtin_amdgcn_exp2f(s[j][0] - m_q[f]);
        float p1 = __builtin_amdgcn_exp2f(s[j][1] - m_q[f]);
        float p2 = __builtin_amdgcn_exp2f(s[j][2] - m_q[f]);
        float p3 = __builtin_amdgcn_exp2f(s[j][3] - m_q[f]);
        lacc += (p0 + p1) + (p2 + p3);
        us4 pk;
        pk[0] = f2bf(p0); pk[1] = f2bf(p1); pk[2] = f2bf(p2); pk[3] = f2bf(p3);
        int swc = (2 * j + (lhi >> 1)) ^ psw;
        *(us4*)(rowb + swc * 16 + (lhi & 1) * 8) = pk;
      }
      l_q[f] += lacc;
    }

    // ---- P back as A-frag (row=q=llo, k=keys lhi*8+e); write latency hidden ----
    short8 pa[4][2];
#pragma unroll
    for (int f = 0; f < 4; ++f) {
      char* rowb = lpw + (f * 16 + llo) * 128;
      pa[f][0] = *(const short8*)(rowb + ((lhi ^ psw) << 4));
      pa[f][1] = *(const short8*)(rowb + (((lhi + 4) ^ psw) << 4));
    }

    // ---- PV: ctx[q][dim] += P * V (V fragments shared across 4 frags) ----
    __builtin_amdgcn_s_setprio(1);
#pragma unroll
    for (int j = 0; j < 4; ++j) {
#pragma unroll
      for (int f = 0; f < 4; ++f) {
        ctxa[f][j] = mfma16(pa[f][0], vb[2 * j], ctxa[f][j]);
        ctxa[f][j] = mfma16(pa[f][1], vb[2 * j + 1], ctxa[f][j]);
      }
    }
    __builtin_amdgcn_s_setprio(0);

    if (t < t1) {                            // rotate double buffer (reg renames)
#pragma unroll
      for (int j = 0; j < 8; ++j) kbA[j] = kbB[j];
    }
  }

  const int b = bh >> 4, h = bh & 15;
#pragma unroll
  for (int f = 0; f < 4; ++f) {
    float lt = l_q[f];                       // reduce lane-partial denom (epilogue only)
    lt += __shfl_xor(lt, 16);
    lt += __shfl_xor(lt, 32);
    float li = 1.0f / lt;
#pragma unroll
    for (int r = 0; r < 4; ++r) {
      float linv = __shfl(li, (lane & 48) | (lhi * 4 + r));
      int qrow = wq0 + f * 16 + lhi * 4 + r;
      size_t base = ((size_t)b * L_ + qrow) * DM_ + h * DH_;
#pragma unroll
      for (int j = 0; j < 4; ++j)
        __builtin_nontemporal_store(f2bf(ctxa[f][j][r] * linv), &CTX[base + j * 16 + llo]);
    }
  }
}

// ---------------- launch ----------------
extern "C" void kernel_launch(void* const* d_in, const int* in_sizes, int n_in,
                              void* d_out, int out_size, void* d_ws, size_t ws_size,
                              hipStream_t stream) {
  (void)in_sizes; (void)n_in; (void)out_size; (void)ws_size;
  const float* x    = (const float*)d_in[0];
  // d_in[1] = attn_mask (all ones) -- unused
  const float* wqkv = (const float*)d_in[2];
  const float* wout = (const float*)d_in[3];
  float* out = (float*)d_out;

  char* w = (char*)d_ws;
  unsigned short* X   = (unsigned short*)(w);                         // 16MB (aliased by CTX)
  unsigned short* WQT = (unsigned short*)(w + 16777216);              // 6MB
  unsigned short* POT = (unsigned short*)(w + 23068672);              // 2MB
  float*          COS = (float*)(w + 25165824);                       // 128KB
  float*          SIN = (float*)(w + 25296896);                       // 128KB
  unsigned short* Qb  = (unsigned short*)(w + 25427968);              // 16MB
  unsigned short* Kb  = (unsigned short*)(w + 25427968 + 16777216);   // 16MB
  unsigned short* Vb  = (unsigned short*)(w + 25427968 + 2*16777216); // 16MB
  unsigned short* VTb = (unsigned short*)(w + 25427968 + 3*16777216); // 16MB
  unsigned short* CTX = X;   // x dead after k_gemm_qkv; reuse for ctx

  k_cvt<<<dim3(8192), dim3(256), 0, stream>>>(x, X, M_ * DM_);
  k_wt<<<dim3(96, 32), dim3(256), 0, stream>>>(wqkv, WQT, 3072);
  k_wt<<<dim3(32, 32), dim3(256), 0, stream>>>(wout, POT, 1024);
  k_rope<<<dim3(128), dim3(256), 0, stream>>>(COS, SIN);
  k_gemm_qkv<<<dim3(1536), dim3(256), 0, stream>>>(X, WQT, Qb, Kb, Vb, COS, SIN);
  k_vt<<<dim3(32, 64), dim3(256), 0, stream>>>(Vb, VTb);
  k_attn<<<dim3(64, 8), dim3(256), 0, stream>>>(Qb, Kb, VTb, CTX);
  k_gemm_out<<<dim3(512), dim3(256), 0, stream>>>(CTX, POT, out);
}